// Round 6
// baseline (351.791 us; speedup 1.0000x reference)
//
#include <hip/hip_runtime.h>
#include <stdint.h>

#define SEQ 256
#define BATCH 32
#define IN_DIM 1024
#define HID 64
#define NPAD 1280
#define ROWS (SEQ*BATCH)   // 8192

// workspace byte offsets (all 256B aligned)
#define XBF_OFF   0
#define WBF_OFF   16777216
#define BB_OFF    19398656
#define GATE_OFF  19403776
#define Y_OFF     19534848
#define DM8_OFF   61477888   // 8-chunk ΔM (37,748,736 B) -> needs ws >= 99,226,624
#define DM8_END   99226624
// 4-chunk fallback ΔM (18,874,368 B) overlays Xbf/Wbf (dead after gemm)

typedef __attribute__((ext_vector_type(8))) short short8;
typedef __attribute__((ext_vector_type(4))) float floatx4;

static __device__ __forceinline__ short f2bf(float f) {
  union { float f; uint32_t u; } a; a.f = f;
  uint32_t r = (a.u + 0x7FFFu + ((a.u >> 16) & 1u)) >> 16;  // RNE
  return (short)r;
}

// ---------------- prep: fp32 -> bf16 for X, concat+convert weights, concat bias ----------------
__global__ void prep_kernel(const float* __restrict__ X,
                            const float* __restrict__ Wk, const float* __restrict__ bk,
                            const float* __restrict__ Wv, const float* __restrict__ bv,
                            const float* __restrict__ Wg, const float* __restrict__ bg,
                            const float* __restrict__ Wq, const float* __restrict__ bq,
                            short* __restrict__ Xbf, short* __restrict__ Wbf,
                            float* __restrict__ bb)
{
  int64_t idx = (int64_t)blockIdx.x * blockDim.x + threadIdx.x;
  int64_t stride = (int64_t)gridDim.x * blockDim.x;
  const int64_t NX4 = (int64_t)ROWS * IN_DIM / 4;
  for (int64_t i = idx; i < NX4; i += stride) {
    float4 x = ((const float4*)X)[i];
    short4 s4;
    s4.x = f2bf(x.x); s4.y = f2bf(x.y); s4.z = f2bf(x.z); s4.w = f2bf(x.w);
    ((short4*)Xbf)[i] = s4;
  }
  const int64_t NW4 = (int64_t)NPAD * IN_DIM / 4;
  for (int64_t i = idx; i < NW4; i += stride) {
    int64_t e = i * 4;
    int r = (int)(e >> 10);
    int k = (int)(e & 1023);
    float4 x;
    if (r < 576)       x = *(const float4*)(Wk + (int64_t)r*1024 + k);
    else if (r < 1152) x = *(const float4*)(Wv + (int64_t)(r-576)*1024 + k);
    else if (r < 1216) x = *(const float4*)(Wq + (int64_t)(r-1152)*1024 + k);
    else               x = make_float4(0.f, 0.f, 0.f, 0.f);   // gate cols unused (fp32 gate kernel)
    short4 s4;
    s4.x = f2bf(x.x); s4.y = f2bf(x.y); s4.z = f2bf(x.z); s4.w = f2bf(x.w);
    ((short4*)Wbf)[i] = s4;
  }
  for (int64_t i = idx; i < NPAD; i += stride) {
    int r = (int)i; float v;
    if (r < 576)       v = bk[r];
    else if (r < 1152) v = bv[r - 576];
    else if (r < 1216) v = bq[r - 1152];
    else               v = 0.f;
    bb[r] = v;
  }
}

// ---------------- GEMM: Y[8192,1280] = Xbf @ Wbf^T + bb (bf16 MFMA, fp32 accum) ----------------
__global__ __launch_bounds__(256) void gemm_kernel(
    const short* __restrict__ Xbf,
    const short* __restrict__ Wbf,
    const float* __restrict__ bb,
    float* __restrict__ Y)
{
  __shared__ short8 AsV[256];  // 64 rows x 32 k, bf16
  __shared__ short8 BsV[256];
  short* As = (short*)AsV;
  short* Bs = (short*)BsV;

  const int tid  = threadIdx.x;
  const int lane = tid & 63;
  const int wv   = tid >> 6;     // 0..3
  const int quad = lane >> 4;    // 0..3
  const int cl   = lane & 15;
  const int m0 = blockIdx.y * 64;
  const int n0 = blockIdx.x * 64;

  const int srow = tid >> 2;         // 0..63
  const int scol = (tid & 3) * 8;    // 0,8,16,24
  const short* gA = Xbf + (int64_t)(m0 + srow) * IN_DIM + scol;
  const short* gB = Wbf + (int64_t)(n0 + srow) * IN_DIM + scol;
  short8* lA = (short8*)&As[srow * 32 + scol];
  short8* lB = (short8*)&Bs[srow * 32 + scol];

  floatx4 acc[4];
#pragma unroll
  for (int i = 0; i < 4; i++) acc[i] = (floatx4){0.f, 0.f, 0.f, 0.f};

  for (int ks = 0; ks < IN_DIM; ks += 32) {
    short8 ra = *(const short8*)(gA + ks);
    short8 rb = *(const short8*)(gB + ks);
    *lA = ra;
    *lB = rb;
    __syncthreads();
    short8 bfrag = *(const short8*)(&Bs[(wv * 16 + cl) * 32 + quad * 8]);
#pragma unroll
    for (int mt = 0; mt < 4; mt++) {
      short8 afrag = *(const short8*)(&As[(mt * 16 + cl) * 32 + quad * 8]);
      acc[mt] = __builtin_amdgcn_mfma_f32_16x16x32_bf16(afrag, bfrag, acc[mt], 0, 0, 0);
    }
    __syncthreads();
  }

  const int col = n0 + wv * 16 + cl;
  const float bias = bb[col];
#pragma unroll
  for (int mt = 0; mt < 4; mt++) {
#pragma unroll
    for (int r = 0; r < 4; r++) {
      int row = m0 + mt * 16 + quad * 4 + r;
      Y[(int64_t)row * NPAD + col] = acc[mt][r] + bias;
    }
  }
}

// ---------------- gate (fp32-exact): logits from X,Wg; top-2 + renormalized weights ----------------
__global__ __launch_bounds__(256) void gate_kernel(
    const float* __restrict__ X,
    const float* __restrict__ Wg, const float* __restrict__ bg,
    float4* __restrict__ gate)
{
  const int lane = threadIdx.x & 63;
  const int row  = blockIdx.x * 4 + (threadIdx.x >> 6);
  const float* x = X + (int64_t)row * IN_DIM;

  float acc[8];
#pragma unroll
  for (int e = 0; e < 8; e++) acc[e] = 0.f;

#pragma unroll
  for (int i = 0; i < 4; i++) {
    const int off = i * 256 + lane * 4;
    float4 xv = *(const float4*)(x + off);
#pragma unroll
    for (int e = 0; e < 8; e++) {
      float4 wv = *(const float4*)(Wg + e * IN_DIM + off);
      acc[e] += xv.x * wv.x + xv.y * wv.y + xv.z * wv.z + xv.w * wv.w;
    }
  }
#pragma unroll
  for (int e = 0; e < 8; e++) {
#pragma unroll
    for (int m = 32; m >= 1; m >>= 1)
      acc[e] += __shfl_xor(acc[e], m);
    acc[e] += bg[e];
  }

  if (lane == 0) {
    int i0 = 0; float v0 = acc[0];
#pragma unroll
    for (int e = 1; e < 8; e++) if (acc[e] > v0) { v0 = acc[e]; i0 = e; }
    int i1 = -1; float v1 = -3.4e38f;
#pragma unroll
    for (int e = 0; e < 8; e++) if (e != i0 && acc[e] > v1) { v1 = acc[e]; i1 = e; }
    float e1 = __expf(v1 - v0);
    float inv = 1.f / (1.f + e1);
    gate[row] = make_float4(__int_as_float(i0), __int_as_float(i1), inv, e1 * inv);
  }
}

// 16-lane (DPP row) sum; result valid in lane (lane&15)==15 of each row.
static __device__ __forceinline__ float row16_sum(float x) {
  float r = x;
  r += __int_as_float(__builtin_amdgcn_update_dpp(0, __float_as_int(r), 0x118, 0xf, 0xf, false)); // row_shr:8
  r += __int_as_float(__builtin_amdgcn_update_dpp(0, __float_as_int(r), 0x114, 0xf, 0xf, false)); // row_shr:4
  r += __int_as_float(__builtin_amdgcn_update_dpp(0, __float_as_int(r), 0x112, 0xf, 0xf, false)); // row_shr:2
  r += __int_as_float(__builtin_amdgcn_update_dpp(0, __float_as_int(r), 0x111, 0xf, 0xf, false)); // row_shr:1
  return r;
}

// ======================= chunked scan =======================
// Decomposition: M_t = Mstart(chunk) + intra-chunk updates. Three phases:
//  A) per-(b,chunk,j-octant): ΔM in registers (order-independent within slot)
//  B) in-place exclusive prefix over chunks (+M0) -> DM[c] becomes Mstart(c)
//  C) per-(b,chunk,j-octant): R4 recurrence body over L steps from Mstart(c)
// Thread layout (A and C): 128 thr = 2 waves; lane&15 -> i-block of 4,
// j = jblk*8 + wave*4 + (lane>>4).  Grid = 32*nc*8 blocks.

#define YROW(tt) (Y + ((int64_t)(tt) * BATCH + b) * NPAD)

// ---------------- phase A: per-chunk delta accumulation ----------------
__global__ __launch_bounds__(128, 4) void chunk_accum_kernel(
    const float* __restrict__ Y, const float4* __restrict__ gate,
    float* __restrict__ DM, int ncMask, int ncShift, int L)
{
  const int blk  = blockIdx.x;
  const int c    = blk & ncMask;
  const int rest = blk >> ncShift;
  const int jblk = rest & 7;
  const int b    = rest >> 3;
  const int tid  = threadIdx.x;
  const int lane = tid & 63;
  const int wv   = tid >> 6;        // 0..1
  const int igrp = lane & 15;
  const int jloc = lane >> 4;
  const int j    = jblk * 8 + wv * 4 + jloc;
  const int ib   = igrp * 4;
  const int t0   = c * L;

  float D[9][4];
#pragma unroll
  for (int m = 0; m < 9; m++)
#pragma unroll
    for (int ii = 0; ii < 4; ii++) D[m][ii] = 0.f;

#define LOAD_A(G, K0, V0, KA, VA, KB, VB) {                 \
    const int li0 = __float_as_int((G).x);                  \
    const int li1 = __float_as_int((G).y);                  \
    const float* Yp = YROW_t;                               \
    K0 = *(const float4*)((Yp) + ib);                       \
    V0 = (Yp)[576 + j];                                     \
    KA = *(const float4*)((Yp) + li0 * 64 + ib);            \
    VA = (Yp)[576 + li0 * 64 + j];                          \
    KB = *(const float4*)((Yp) + li1 * 64 + ib);            \
    VB = (Yp)[576 + li1 * 64 + j]; }

#define ACC(mm, KK, VV) {                                   \
    D[mm][0] += KK.x * VV; D[mm][1] += KK.y * VV;           \
    D[mm][2] += KK.z * VV; D[mm][3] += KK.w * VV; }

#define COMPA(G, K0, V0, KA, VA, KB, VB) {                  \
    const int i0 = __float_as_int((G).x);                   \
    const int i1 = __float_as_int((G).y);                   \
    ACC(0, K0, V0);                                         \
    switch (i0) {                                           \
      case 0: ACC(0, KA, VA); break;                        \
      case 1: ACC(1, KA, VA); break;                        \
      case 2: ACC(2, KA, VA); break;                        \
      case 3: ACC(3, KA, VA); break;                        \
      case 4: ACC(4, KA, VA); break;                        \
      case 5: ACC(5, KA, VA); break;                        \
      case 6: ACC(6, KA, VA); break;                        \
      default: ACC(7, KA, VA); break;                       \
    }                                                       \
    switch (i1) {                                           \
      case 0: ACC(0, KB, VB); break;                        \
      case 1: ACC(1, KB, VB); break;                        \
      case 2: ACC(2, KB, VB); break;                        \
      case 3: ACC(3, KB, VB); break;                        \
      case 4: ACC(4, KB, VB); break;                        \
      case 5: ACC(5, KB, VB); break;                        \
      case 6: ACC(6, KB, VB); break;                        \
      default: ACC(7, KB, VB); break;                       \
    } }

  // distance-2 two-buffer prefetch (same shape as the proven R4 loop)
  float4 g0 = gate[t0 * BATCH + b];
  float4 g1 = gate[(t0 + 1) * BATCH + b];
  float4 g2 = gate[((t0 + 2 < SEQ) ? t0 + 2 : SEQ - 1) * BATCH + b];

  float4 k00, ka0, kb0; float v00, va0, vb0;
  float4 k01, ka1, kb1; float v01, va1, vb1;
  { const float* YROW_t = YROW(t0);     LOAD_A(g0, k00, v00, ka0, va0, kb0, vb0); }
  { const float* YROW_t = YROW(t0 + 1); LOAD_A(g1, k01, v01, ka1, va1, kb1, vb1); }

  for (int t = t0; t < t0 + L; t += 2) {
    {
      const int tl = (t + 2 < SEQ) ? t + 2 : SEQ - 1;
      const int tg = (t + 3 < SEQ) ? t + 3 : SEQ - 1;
      float4 gnew = gate[tg * BATCH + b];
      float4 nk0, nka, nkb; float nv0, nva, nvb;
      { const float* YROW_t = YROW(tl); LOAD_A(g2, nk0, nv0, nka, nva, nkb, nvb); }
      COMPA(g0, k00, v00, ka0, va0, kb0, vb0);
      k00 = nk0; v00 = nv0; ka0 = nka; va0 = nva; kb0 = nkb; vb0 = nvb;
      g0 = g1; g1 = g2; g2 = gnew;
    }
    {
      const int tl = (t + 3 < SEQ) ? t + 3 : SEQ - 1;
      const int tg = (t + 4 < SEQ) ? t + 4 : SEQ - 1;
      float4 gnew = gate[tg * BATCH + b];
      float4 nk0, nka, nkb; float nv0, nva, nvb;
      { const float* YROW_t = YROW(tl); LOAD_A(g2, nk0, nv0, nka, nva, nkb, nvb); }
      COMPA(g0, k01, v01, ka1, va1, kb1, vb1);
      k01 = nk0; v01 = nv0; ka1 = nka; va1 = nva; kb1 = nkb; vb1 = nvb;
      g0 = g1; g1 = g2; g2 = gnew;
    }
  }
#undef COMPA
#undef ACC
#undef LOAD_A

  float* dmb = DM + ((int64_t)(c * 32 + b)) * 36864;
#pragma unroll
  for (int m = 0; m < 9; m++)
#pragma unroll
    for (int ii = 0; ii < 4; ii++)
      dmb[m * 4096 + (ib + ii) * 64 + j] = D[m][ii];
}

// ---------------- phase B: in-place exclusive prefix (+M0) over chunks ----------------
__global__ void prefix_kernel(const float* __restrict__ M0, float* __restrict__ DM, int nc)
{
  int64_t e = (int64_t)blockIdx.x * blockDim.x + threadIdx.x;   // < 32*36864
  int b = (int)(e / 36864);
  int r = (int)(e % 36864);
  float run = M0[e];
  for (int cc = 0; cc < nc; cc++) {
    int64_t idx = ((int64_t)(cc * 32 + b)) * 36864 + r;
    float tmp = DM[idx];
    DM[idx] = run;
    run += tmp;
  }
}

// ---------------- phase C: intra-chunk recurrence + readout ----------------
__global__ __launch_bounds__(128, 4) void chunk_scan_kernel(
    const float* __restrict__ Y, const float4* __restrict__ gate,
    const float* __restrict__ DM,   // holds Mstart(c) after prefix
    float* __restrict__ out, int ncMask, int ncShift, int L)
{
  const int blk  = blockIdx.x;
  const int c    = blk & ncMask;
  const int rest = blk >> ncShift;
  const int jblk = rest & 7;
  const int b    = rest >> 3;
  const int tid  = threadIdx.x;
  const int lane = tid & 63;
  const int wv   = tid >> 6;        // 0..1
  const int igrp = lane & 15;
  const int jloc = lane >> 4;
  const int j    = jblk * 8 + wv * 4 + jloc;
  const int ib   = igrp * 4;
  const int t0   = c * L;

  float M[9][4];
  const float* msb = DM + ((int64_t)(c * 32 + b)) * 36864;
#pragma unroll
  for (int m = 0; m < 9; m++)
#pragma unroll
    for (int ii = 0; ii < 4; ii++)
      M[m][ii] = msb[m * 4096 + (ib + ii) * 64 + j];

#define LOAD_C(G, Q, K0, V0, KA, VA, KB, VB) {              \
    const int li0 = __float_as_int((G).x);                  \
    const int li1 = __float_as_int((G).y);                  \
    const float* Yp = YROW_t;                               \
    Q  = *(const float4*)((Yp) + 1152 + ib);                \
    K0 = *(const float4*)((Yp) + ib);                       \
    V0 = (Yp)[576 + j];                                     \
    KA = *(const float4*)((Yp) + li0 * 64 + ib);            \
    VA = (Yp)[576 + li0 * 64 + j];                          \
    KB = *(const float4*)((Yp) + li1 * 64 + ib);            \
    VB = (Yp)[576 + li1 * 64 + j]; }

#define DO_SLOT(mm, gw, KK, VV) {                                            \
      M[mm][0] += KK.x * VV; M[mm][1] += KK.y * VV;                          \
      M[mm][2] += KK.z * VV; M[mm][3] += KK.w * VV;                          \
      Mc0 += (gw) * M[mm][0]; Mc1 += (gw) * M[mm][1];                        \
      Mc2 += (gw) * M[mm][2]; Mc3 += (gw) * M[mm][3]; }

    // routed slot == 0: add the delta unweighted too (all scatter-adds precede readout)
#define DO_SLOT0(gw, KK, VV) {                                               \
      float d0 = KK.x * VV, d1 = KK.y * VV, d2 = KK.z * VV, d3 = KK.w * VV;  \
      M[0][0] += d0; M[0][1] += d1; M[0][2] += d2; M[0][3] += d3;            \
      Mc0 += d0 + (gw) * M[0][0]; Mc1 += d1 + (gw) * M[0][1];                \
      Mc2 += d2 + (gw) * M[0][2]; Mc3 += d3 + (gw) * M[0][3]; }

#define COMPUTE(G, Q, K0, V0, KA, VA, KB, VB, TT) {                          \
    const int i0 = __float_as_int((G).x);                                    \
    const int i1 = __float_as_int((G).y);                                    \
    const float g0w = (G).z, g1w = (G).w;                                    \
    float Mc0, Mc1, Mc2, Mc3;                                                \
    M[0][0] += K0.x * V0; M[0][1] += K0.y * V0;                              \
    M[0][2] += K0.z * V0; M[0][3] += K0.w * V0;                              \
    Mc0 = M[0][0]; Mc1 = M[0][1]; Mc2 = M[0][2]; Mc3 = M[0][3];              \
    switch (i0) {                                                            \
      case 0: DO_SLOT0(g0w, KA, VA); break;                                  \
      case 1: DO_SLOT(1, g0w, KA, VA); break;                                \
      case 2: DO_SLOT(2, g0w, KA, VA); break;                                \
      case 3: DO_SLOT(3, g0w, KA, VA); break;                                \
      case 4: DO_SLOT(4, g0w, KA, VA); break;                                \
      case 5: DO_SLOT(5, g0w, KA, VA); break;                                \
      case 6: DO_SLOT(6, g0w, KA, VA); break;                                \
      default: DO_SLOT(7, g0w, KA, VA); break;                               \
    }                                                                        \
    switch (i1) {                                                            \
      case 0: DO_SLOT0(g1w, KB, VB); break;                                  \
      case 1: DO_SLOT(1, g1w, KB, VB); break;                                \
      case 2: DO_SLOT(2, g1w, KB, VB); break;                                \
      case 3: DO_SLOT(3, g1w, KB, VB); break;                                \
      case 4: DO_SLOT(4, g1w, KB, VB); break;                                \
      case 5: DO_SLOT(5, g1w, KB, VB); break;                                \
      case 6: DO_SLOT(6, g1w, KB, VB); break;                                \
      default: DO_SLOT(7, g1w, KB, VB); break;                               \
    }                                                                        \
    float part = Q.x * Mc0 + Q.y * Mc1 + Q.z * Mc2 + Q.w * Mc3;              \
    part = row16_sum(part);                                                  \
    if (igrp == 15)                                                          \
      out[(int64_t)(TT) * (BATCH * HID) + b * HID + j] = part; }

  float4 g0 = gate[t0 * BATCH + b];
  float4 g1 = gate[(t0 + 1) * BATCH + b];
  float4 g2 = gate[((t0 + 2 < SEQ) ? t0 + 2 : SEQ - 1) * BATCH + b];

  float4 q0v, k00, ka0, kb0; float v00, va0, vb0;
  float4 q1v, k01, ka1, kb1; float v01, va1, vb1;
  { const float* YROW_t = YROW(t0);     LOAD_C(g0, q0v, k00, v00, ka0, va0, kb0, vb0); }
  { const float* YROW_t = YROW(t0 + 1); LOAD_C(g1, q1v, k01, v01, ka1, va1, kb1, vb1); }

  for (int t = t0; t < t0 + L; t += 2) {
    {
      const int tl = (t + 2 < SEQ) ? t + 2 : SEQ - 1;
      const int tg = (t + 3 < SEQ) ? t + 3 : SEQ - 1;
      float4 gnew = gate[tg * BATCH + b];
      float4 nq, nk0, nka, nkb; float nv0, nva, nvb;
      { const float* YROW_t = YROW(tl); LOAD_C(g2, nq, nk0, nv0, nka, nva, nkb, nvb); }
      COMPUTE(g0, q0v, k00, v00, ka0, va0, kb0, vb0, t);
      q0v = nq; k00 = nk0; v00 = nv0; ka0 = nka; va0 = nva; kb0 = nkb; vb0 = nvb;
      g0 = g1; g1 = g2; g2 = gnew;
    }
    {
      const int tl = (t + 3 < SEQ) ? t + 3 : SEQ - 1;
      const int tg = (t + 4 < SEQ) ? t + 4 : SEQ - 1;
      float4 gnew = gate[tg * BATCH + b];
      float4 nq, nk0, nka, nkb; float nv0, nva, nvb;
      { const float* YROW_t = YROW(tl); LOAD_C(g2, nq, nk0, nv0, nka, nva, nkb, nvb); }
      COMPUTE(g0, q1v, k01, v01, ka1, va1, kb1, vb1, t + 1);
      q1v = nq; k01 = nk0; v01 = nv0; ka1 = nka; va1 = nva; kb1 = nkb; vb1 = nvb;
      g0 = g1; g1 = g2; g2 = gnew;
    }
  }
#undef COMPUTE
#undef DO_SLOT
#undef DO_SLOT0
#undef LOAD_C

  if (c == ncMask) {   // last chunk owns M_final
    float* Mf = out + (int64_t)SEQ * BATCH * HID + (int64_t)b * 36864;
#pragma unroll
    for (int m = 0; m < 9; m++)
#pragma unroll
      for (int ii = 0; ii < 4; ii++)
        Mf[m * 4096 + (ib + ii) * 64 + j] = M[m][ii];
  }
}

// ---------------- launch ----------------
extern "C" void kernel_launch(void* const* d_in, const int* in_sizes, int n_in,
                              void* d_out, int out_size, void* d_ws, size_t ws_size,
                              hipStream_t stream)
{
  const float* X  = (const float*)d_in[0];
  const float* M0 = (const float*)d_in[1];
  const float* Wk = (const float*)d_in[2];
  const float* bk = (const float*)d_in[3];
  const float* Wv = (const float*)d_in[4];
  const float* bv = (const float*)d_in[5];
  const float* Wg = (const float*)d_in[6];
  const float* bg = (const float*)d_in[7];
  const float* Wq = (const float*)d_in[8];
  const float* bq = (const float*)d_in[9];

  char* ws = (char*)d_ws;
  short*  Xbf  = (short*)(ws + XBF_OFF);
  short*  Wbf  = (short*)(ws + WBF_OFF);
  float*  bb   = (float*)(ws + BB_OFF);
  float4* gate = (float4*)(ws + GATE_OFF);
  float*  Y    = (float*)(ws + Y_OFF);
  float*  out  = (float*)d_out;

  // chunk count: 8 if ws has room for a fresh ΔM region; else 4 chunks reusing
  // the Xbf/Wbf region (dead after gemm). ws_size is constant per deployment,
  // so this branch is deterministic across calls (graph-safe).
  int nc, ncShift; size_t dm_off;
  if (ws_size >= (size_t)DM8_END) { nc = 8; ncShift = 3; dm_off = DM8_OFF; }
  else                            { nc = 4; ncShift = 2; dm_off = 0; }
  const int L = SEQ / nc;
  float* DM = (float*)(ws + dm_off);

  prep_kernel<<<2048, 256, 0, stream>>>(X, Wk, bk, Wv, bv, Wg, bg, Wq, bq, Xbf, Wbf, bb);
  gate_kernel<<<ROWS / 4, 256, 0, stream>>>(X, Wg, bg, gate);
  dim3 gg(NPAD / 64, ROWS / 64);
  gemm_kernel<<<gg, 256, 0, stream>>>(Xbf, Wbf, bb, Y);
  chunk_accum_kernel<<<32 * nc * 8, 128, 0, stream>>>(Y, gate, DM, nc - 1, ncShift, L);
  prefix_kernel<<<(32 * 36864) / 256, 256, 0, stream>>>(M0, DM, nc);
  chunk_scan_kernel<<<32 * nc * 8, 128, 0, stream>>>(Y, gate, DM, out, nc - 1, ncShift, L);
}

// Round 7
// 299.171 us; speedup vs baseline: 1.1759x; 1.1759x over previous
//
#include <hip/hip_runtime.h>
#include <stdint.h>

#define SEQ 256
#define BATCH 32
#define IN_DIM 1024
#define HID 64
#define NPAD 1280
#define ROWS (SEQ*BATCH)   // 8192

// workspace byte offsets (all 256B aligned)
#define XBF_OFF   0
#define WBF_OFF   16777216
#define BB_OFF    19398656
#define GATE_OFF  19403776
#define Y_OFF     19534848
#define DM8_OFF   61477888   // 8-chunk ΔM (37,748,736 B) -> needs ws >= 99,226,624
#define DM8_END   99226624
// 4-chunk fallback ΔM (18,874,368 B) overlays Xbf/Wbf (dead after gemm)

typedef __attribute__((ext_vector_type(8))) short short8;
typedef __attribute__((ext_vector_type(4))) float floatx4;

static __device__ __forceinline__ short f2bf(float f) {
  union { float f; uint32_t u; } a; a.f = f;
  uint32_t r = (a.u + 0x7FFFu + ((a.u >> 16) & 1u)) >> 16;  // RNE
  return (short)r;
}

// ---------------- prep: fp32 -> bf16 for X, concat+convert weights, concat bias ----------------
__global__ void prep_kernel(const float* __restrict__ X,
                            const float* __restrict__ Wk, const float* __restrict__ bk,
                            const float* __restrict__ Wv, const float* __restrict__ bv,
                            const float* __restrict__ Wg, const float* __restrict__ bg,
                            const float* __restrict__ Wq, const float* __restrict__ bq,
                            short* __restrict__ Xbf, short* __restrict__ Wbf,
                            float* __restrict__ bb)
{
  int64_t idx = (int64_t)blockIdx.x * blockDim.x + threadIdx.x;
  int64_t stride = (int64_t)gridDim.x * blockDim.x;
  const int64_t NX4 = (int64_t)ROWS * IN_DIM / 4;
  for (int64_t i = idx; i < NX4; i += stride) {
    float4 x = ((const float4*)X)[i];
    short4 s4;
    s4.x = f2bf(x.x); s4.y = f2bf(x.y); s4.z = f2bf(x.z); s4.w = f2bf(x.w);
    ((short4*)Xbf)[i] = s4;
  }
  const int64_t NW4 = (int64_t)NPAD * IN_DIM / 4;
  for (int64_t i = idx; i < NW4; i += stride) {
    int64_t e = i * 4;
    int r = (int)(e >> 10);
    int k = (int)(e & 1023);
    float4 x;
    if (r < 576)       x = *(const float4*)(Wk + (int64_t)r*1024 + k);
    else if (r < 1152) x = *(const float4*)(Wv + (int64_t)(r-576)*1024 + k);
    else if (r < 1216) x = *(const float4*)(Wq + (int64_t)(r-1152)*1024 + k);
    else               x = make_float4(0.f, 0.f, 0.f, 0.f);   // gate cols unused (fp32 gate kernel)
    short4 s4;
    s4.x = f2bf(x.x); s4.y = f2bf(x.y); s4.z = f2bf(x.z); s4.w = f2bf(x.w);
    ((short4*)Wbf)[i] = s4;
  }
  for (int64_t i = idx; i < NPAD; i += stride) {
    int r = (int)i; float v;
    if (r < 576)       v = bk[r];
    else if (r < 1152) v = bv[r - 576];
    else if (r < 1216) v = bq[r - 1152];
    else               v = 0.f;
    bb[r] = v;
  }
}

// ---------------- GEMM: Y[8192,1280] = Xbf @ Wbf^T + bb (bf16 MFMA, fp32 accum) ----------------
__global__ __launch_bounds__(256) void gemm_kernel(
    const short* __restrict__ Xbf,
    const short* __restrict__ Wbf,
    const float* __restrict__ bb,
    float* __restrict__ Y)
{
  __shared__ short8 AsV[256];  // 64 rows x 32 k, bf16
  __shared__ short8 BsV[256];
  short* As = (short*)AsV;
  short* Bs = (short*)BsV;

  const int tid  = threadIdx.x;
  const int lane = tid & 63;
  const int wv   = tid >> 6;     // 0..3
  const int quad = lane >> 4;    // 0..3
  const int cl   = lane & 15;
  const int m0 = blockIdx.y * 64;
  const int n0 = blockIdx.x * 64;

  const int srow = tid >> 2;         // 0..63
  const int scol = (tid & 3) * 8;    // 0,8,16,24
  const short* gA = Xbf + (int64_t)(m0 + srow) * IN_DIM + scol;
  const short* gB = Wbf + (int64_t)(n0 + srow) * IN_DIM + scol;
  short8* lA = (short8*)&As[srow * 32 + scol];
  short8* lB = (short8*)&Bs[srow * 32 + scol];

  floatx4 acc[4];
#pragma unroll
  for (int i = 0; i < 4; i++) acc[i] = (floatx4){0.f, 0.f, 0.f, 0.f};

  for (int ks = 0; ks < IN_DIM; ks += 32) {
    short8 ra = *(const short8*)(gA + ks);
    short8 rb = *(const short8*)(gB + ks);
    *lA = ra;
    *lB = rb;
    __syncthreads();
    short8 bfrag = *(const short8*)(&Bs[(wv * 16 + cl) * 32 + quad * 8]);
#pragma unroll
    for (int mt = 0; mt < 4; mt++) {
      short8 afrag = *(const short8*)(&As[(mt * 16 + cl) * 32 + quad * 8]);
      acc[mt] = __builtin_amdgcn_mfma_f32_16x16x32_bf16(afrag, bfrag, acc[mt], 0, 0, 0);
    }
    __syncthreads();
  }

  const int col = n0 + wv * 16 + cl;
  const float bias = bb[col];
#pragma unroll
  for (int mt = 0; mt < 4; mt++) {
#pragma unroll
    for (int r = 0; r < 4; r++) {
      int row = m0 + mt * 16 + quad * 4 + r;
      Y[(int64_t)row * NPAD + col] = acc[mt][r] + bias;
    }
  }
}

// ---------------- gate (fp32-exact): logits from X,Wg; top-2 + renormalized weights ----------------
__global__ __launch_bounds__(256) void gate_kernel(
    const float* __restrict__ X,
    const float* __restrict__ Wg, const float* __restrict__ bg,
    float4* __restrict__ gate)
{
  const int lane = threadIdx.x & 63;
  const int row  = blockIdx.x * 4 + (threadIdx.x >> 6);
  const float* x = X + (int64_t)row * IN_DIM;

  float acc[8];
#pragma unroll
  for (int e = 0; e < 8; e++) acc[e] = 0.f;

#pragma unroll
  for (int i = 0; i < 4; i++) {
    const int off = i * 256 + lane * 4;
    float4 xv = *(const float4*)(x + off);
#pragma unroll
    for (int e = 0; e < 8; e++) {
      float4 wv = *(const float4*)(Wg + e * IN_DIM + off);
      acc[e] += xv.x * wv.x + xv.y * wv.y + xv.z * wv.z + xv.w * wv.w;
    }
  }
#pragma unroll
  for (int e = 0; e < 8; e++) {
#pragma unroll
    for (int m = 32; m >= 1; m >>= 1)
      acc[e] += __shfl_xor(acc[e], m);
    acc[e] += bg[e];
  }

  if (lane == 0) {
    int i0 = 0; float v0 = acc[0];
#pragma unroll
    for (int e = 1; e < 8; e++) if (acc[e] > v0) { v0 = acc[e]; i0 = e; }
    int i1 = -1; float v1 = -3.4e38f;
#pragma unroll
    for (int e = 0; e < 8; e++) if (e != i0 && acc[e] > v1) { v1 = acc[e]; i1 = e; }
    float e1 = __expf(v1 - v0);
    float inv = 1.f / (1.f + e1);
    gate[row] = make_float4(__int_as_float(i0), __int_as_float(i1), inv, e1 * inv);
  }
}

// 16-lane (DPP row) sum; result valid in lane (lane&15)==15 of each row.
static __device__ __forceinline__ float row16_sum(float x) {
  float r = x;
  r += __int_as_float(__builtin_amdgcn_update_dpp(0, __float_as_int(r), 0x118, 0xf, 0xf, false)); // row_shr:8
  r += __int_as_float(__builtin_amdgcn_update_dpp(0, __float_as_int(r), 0x114, 0xf, 0xf, false)); // row_shr:4
  r += __int_as_float(__builtin_amdgcn_update_dpp(0, __float_as_int(r), 0x112, 0xf, 0xf, false)); // row_shr:2
  r += __int_as_float(__builtin_amdgcn_update_dpp(0, __float_as_int(r), 0x111, 0xf, 0xf, false)); // row_shr:1
  return r;
}

// ======================= chunked scan =======================
// Decomposition: M_t = Mstart(chunk) + intra-chunk updates. Three phases:
//  A) per-(b,chunk,j-octant): ΔM in registers (order-independent within slot)
//  B) in-place exclusive prefix over chunks (+M0) -> DM[c] becomes Mstart(c)
//  C) per-(b,chunk,j-octant): R4 recurrence body over L steps from Mstart(c)
// Thread layout (A and C): 128 thr = 2 waves; lane&15 -> i-block of 4,
// j = jblk*8 + wave*4 + (lane>>4).  Grid = 32*nc*8 blocks.
// R6 post-mortem: __launch_bounds__(128,4) capped VGPRs so hard the M/D state
// arrays spilled to scratch (VGPR_Count=64, WRITE_SIZE 291MB vs 7MB actual
// output). Default bounds here: R4 proved this body fits ~124-170 regs, and at
// 2-wave blocks occupancy stays ample without a cap.

#define YROW(tt) (Y + ((int64_t)(tt) * BATCH + b) * NPAD)

// ---------------- phase A: per-chunk delta accumulation ----------------
__global__ __launch_bounds__(128) void chunk_accum_kernel(
    const float* __restrict__ Y, const float4* __restrict__ gate,
    float* __restrict__ DM, int ncMask, int ncShift, int L)
{
  const int blk  = blockIdx.x;
  const int c    = blk & ncMask;
  const int rest = blk >> ncShift;
  const int jblk = rest & 7;
  const int b    = rest >> 3;
  const int tid  = threadIdx.x;
  const int lane = tid & 63;
  const int wv   = tid >> 6;        // 0..1
  const int igrp = lane & 15;
  const int jloc = lane >> 4;
  const int j    = jblk * 8 + wv * 4 + jloc;
  const int ib   = igrp * 4;
  const int t0   = c * L;

  float D[9][4];
#pragma unroll
  for (int m = 0; m < 9; m++)
#pragma unroll
    for (int ii = 0; ii < 4; ii++) D[m][ii] = 0.f;

#define LOAD_A(G, K0, V0, KA, VA, KB, VB) {                 \
    const int li0 = __float_as_int((G).x);                  \
    const int li1 = __float_as_int((G).y);                  \
    const float* Yp = YROW_t;                               \
    K0 = *(const float4*)((Yp) + ib);                       \
    V0 = (Yp)[576 + j];                                     \
    KA = *(const float4*)((Yp) + li0 * 64 + ib);            \
    VA = (Yp)[576 + li0 * 64 + j];                          \
    KB = *(const float4*)((Yp) + li1 * 64 + ib);            \
    VB = (Yp)[576 + li1 * 64 + j]; }

#define ACC(mm, KK, VV) {                                   \
    D[mm][0] += KK.x * VV; D[mm][1] += KK.y * VV;           \
    D[mm][2] += KK.z * VV; D[mm][3] += KK.w * VV; }

#define COMPA(G, K0, V0, KA, VA, KB, VB) {                  \
    const int i0 = __float_as_int((G).x);                   \
    const int i1 = __float_as_int((G).y);                   \
    ACC(0, K0, V0);                                         \
    switch (i0) {                                           \
      case 0: ACC(0, KA, VA); break;                        \
      case 1: ACC(1, KA, VA); break;                        \
      case 2: ACC(2, KA, VA); break;                        \
      case 3: ACC(3, KA, VA); break;                        \
      case 4: ACC(4, KA, VA); break;                        \
      case 5: ACC(5, KA, VA); break;                        \
      case 6: ACC(6, KA, VA); break;                        \
      default: ACC(7, KA, VA); break;                       \
    }                                                       \
    switch (i1) {                                           \
      case 0: ACC(0, KB, VB); break;                        \
      case 1: ACC(1, KB, VB); break;                        \
      case 2: ACC(2, KB, VB); break;                        \
      case 3: ACC(3, KB, VB); break;                        \
      case 4: ACC(4, KB, VB); break;                        \
      case 5: ACC(5, KB, VB); break;                        \
      case 6: ACC(6, KB, VB); break;                        \
      default: ACC(7, KB, VB); break;                       \
    } }

  // distance-2 two-buffer prefetch (same shape as the proven R4 loop)
  float4 g0 = gate[t0 * BATCH + b];
  float4 g1 = gate[(t0 + 1) * BATCH + b];
  float4 g2 = gate[((t0 + 2 < SEQ) ? t0 + 2 : SEQ - 1) * BATCH + b];

  float4 k00, ka0, kb0; float v00, va0, vb0;
  float4 k01, ka1, kb1; float v01, va1, vb1;
  { const float* YROW_t = YROW(t0);     LOAD_A(g0, k00, v00, ka0, va0, kb0, vb0); }
  { const float* YROW_t = YROW(t0 + 1); LOAD_A(g1, k01, v01, ka1, va1, kb1, vb1); }

  for (int t = t0; t < t0 + L; t += 2) {
    {
      const int tl = (t + 2 < SEQ) ? t + 2 : SEQ - 1;
      const int tg = (t + 3 < SEQ) ? t + 3 : SEQ - 1;
      float4 gnew = gate[tg * BATCH + b];
      float4 nk0, nka, nkb; float nv0, nva, nvb;
      { const float* YROW_t = YROW(tl); LOAD_A(g2, nk0, nv0, nka, nva, nkb, nvb); }
      COMPA(g0, k00, v00, ka0, va0, kb0, vb0);
      k00 = nk0; v00 = nv0; ka0 = nka; va0 = nva; kb0 = nkb; vb0 = nvb;
      g0 = g1; g1 = g2; g2 = gnew;
    }
    {
      const int tl = (t + 3 < SEQ) ? t + 3 : SEQ - 1;
      const int tg = (t + 4 < SEQ) ? t + 4 : SEQ - 1;
      float4 gnew = gate[tg * BATCH + b];
      float4 nk0, nka, nkb; float nv0, nva, nvb;
      { const float* YROW_t = YROW(tl); LOAD_A(g2, nk0, nv0, nka, nva, nkb, nvb); }
      COMPA(g0, k01, v01, ka1, va1, kb1, vb1);
      k01 = nk0; v01 = nv0; ka1 = nka; va1 = nva; kb1 = nkb; vb1 = nvb;
      g0 = g1; g1 = g2; g2 = gnew;
    }
  }
#undef COMPA
#undef ACC
#undef LOAD_A

  float* dmb = DM + ((int64_t)(c * 32 + b)) * 36864;
#pragma unroll
  for (int m = 0; m < 9; m++)
#pragma unroll
    for (int ii = 0; ii < 4; ii++)
      dmb[m * 4096 + (ib + ii) * 64 + j] = D[m][ii];
}

// ---------------- phase B: in-place exclusive prefix (+M0) over chunks ----------------
__global__ void prefix_kernel(const float* __restrict__ M0, float* __restrict__ DM, int nc)
{
  int64_t e = (int64_t)blockIdx.x * blockDim.x + threadIdx.x;   // < 32*36864
  int b = (int)(e / 36864);
  int r = (int)(e % 36864);
  float run = M0[e];
  for (int cc = 0; cc < nc; cc++) {
    int64_t idx = ((int64_t)(cc * 32 + b)) * 36864 + r;
    float tmp = DM[idx];
    DM[idx] = run;
    run += tmp;
  }
}

// ---------------- phase C: intra-chunk recurrence + readout ----------------
__global__ __launch_bounds__(128) void chunk_scan_kernel(
    const float* __restrict__ Y, const float4* __restrict__ gate,
    const float* __restrict__ DM,   // holds Mstart(c) after prefix
    float* __restrict__ out, int ncMask, int ncShift, int L)
{
  const int blk  = blockIdx.x;
  const int c    = blk & ncMask;
  const int rest = blk >> ncShift;
  const int jblk = rest & 7;
  const int b    = rest >> 3;
  const int tid  = threadIdx.x;
  const int lane = tid & 63;
  const int wv   = tid >> 6;        // 0..1
  const int igrp = lane & 15;
  const int jloc = lane >> 4;
  const int j    = jblk * 8 + wv * 4 + jloc;
  const int ib   = igrp * 4;
  const int t0   = c * L;

  float M[9][4];
  const float* msb = DM + ((int64_t)(c * 32 + b)) * 36864;
#pragma unroll
  for (int m = 0; m < 9; m++)
#pragma unroll
    for (int ii = 0; ii < 4; ii++)
      M[m][ii] = msb[m * 4096 + (ib + ii) * 64 + j];

#define LOAD_C(G, Q, K0, V0, KA, VA, KB, VB) {              \
    const int li0 = __float_as_int((G).x);                  \
    const int li1 = __float_as_int((G).y);                  \
    const float* Yp = YROW_t;                               \
    Q  = *(const float4*)((Yp) + 1152 + ib);                \
    K0 = *(const float4*)((Yp) + ib);                       \
    V0 = (Yp)[576 + j];                                     \
    KA = *(const float4*)((Yp) + li0 * 64 + ib);            \
    VA = (Yp)[576 + li0 * 64 + j];                          \
    KB = *(const float4*)((Yp) + li1 * 64 + ib);            \
    VB = (Yp)[576 + li1 * 64 + j]; }

#define DO_SLOT(mm, gw, KK, VV) {                                            \
      M[mm][0] += KK.x * VV; M[mm][1] += KK.y * VV;                          \
      M[mm][2] += KK.z * VV; M[mm][3] += KK.w * VV;                          \
      Mc0 += (gw) * M[mm][0]; Mc1 += (gw) * M[mm][1];                        \
      Mc2 += (gw) * M[mm][2]; Mc3 += (gw) * M[mm][3]; }

    // routed slot == 0: add the delta unweighted too (all scatter-adds precede readout)
#define DO_SLOT0(gw, KK, VV) {                                               \
      float d0 = KK.x * VV, d1 = KK.y * VV, d2 = KK.z * VV, d3 = KK.w * VV;  \
      M[0][0] += d0; M[0][1] += d1; M[0][2] += d2; M[0][3] += d3;            \
      Mc0 += d0 + (gw) * M[0][0]; Mc1 += d1 + (gw) * M[0][1];                \
      Mc2 += d2 + (gw) * M[0][2]; Mc3 += d3 + (gw) * M[0][3]; }

#define COMPUTE(G, Q, K0, V0, KA, VA, KB, VB, TT) {                          \
    const int i0 = __float_as_int((G).x);                                    \
    const int i1 = __float_as_int((G).y);                                    \
    const float g0w = (G).z, g1w = (G).w;                                    \
    float Mc0, Mc1, Mc2, Mc3;                                                \
    M[0][0] += K0.x * V0; M[0][1] += K0.y * V0;                              \
    M[0][2] += K0.z * V0; M[0][3] += K0.w * V0;                              \
    Mc0 = M[0][0]; Mc1 = M[0][1]; Mc2 = M[0][2]; Mc3 = M[0][3];              \
    switch (i0) {                                                            \
      case 0: DO_SLOT0(g0w, KA, VA); break;                                  \
      case 1: DO_SLOT(1, g0w, KA, VA); break;                                \
      case 2: DO_SLOT(2, g0w, KA, VA); break;                                \
      case 3: DO_SLOT(3, g0w, KA, VA); break;                                \
      case 4: DO_SLOT(4, g0w, KA, VA); break;                                \
      case 5: DO_SLOT(5, g0w, KA, VA); break;                                \
      case 6: DO_SLOT(6, g0w, KA, VA); break;                                \
      default: DO_SLOT(7, g0w, KA, VA); break;                               \
    }                                                                        \
    switch (i1) {                                                            \
      case 0: DO_SLOT0(g1w, KB, VB); break;                                  \
      case 1: DO_SLOT(1, g1w, KB, VB); break;                                \
      case 2: DO_SLOT(2, g1w, KB, VB); break;                                \
      case 3: DO_SLOT(3, g1w, KB, VB); break;                                \
      case 4: DO_SLOT(4, g1w, KB, VB); break;                                \
      case 5: DO_SLOT(5, g1w, KB, VB); break;                                \
      case 6: DO_SLOT(6, g1w, KB, VB); break;                                \
      default: DO_SLOT(7, g1w, KB, VB); break;                               \
    }                                                                        \
    float part = Q.x * Mc0 + Q.y * Mc1 + Q.z * Mc2 + Q.w * Mc3;              \
    part = row16_sum(part);                                                  \
    if (igrp == 15)                                                          \
      out[(int64_t)(TT) * (BATCH * HID) + b * HID + j] = part; }

  float4 g0 = gate[t0 * BATCH + b];
  float4 g1 = gate[(t0 + 1) * BATCH + b];
  float4 g2 = gate[((t0 + 2 < SEQ) ? t0 + 2 : SEQ - 1) * BATCH + b];

  float4 q0v, k00, ka0, kb0; float v00, va0, vb0;
  float4 q1v, k01, ka1, kb1; float v01, va1, vb1;
  { const float* YROW_t = YROW(t0);     LOAD_C(g0, q0v, k00, v00, ka0, va0, kb0, vb0); }
  { const float* YROW_t = YROW(t0 + 1); LOAD_C(g1, q1v, k01, v01, ka1, va1, kb1, vb1); }

  for (int t = t0; t < t0 + L; t += 2) {
    {
      const int tl = (t + 2 < SEQ) ? t + 2 : SEQ - 1;
      const int tg = (t + 3 < SEQ) ? t + 3 : SEQ - 1;
      float4 gnew = gate[tg * BATCH + b];
      float4 nq, nk0, nka, nkb; float nv0, nva, nvb;
      { const float* YROW_t = YROW(tl); LOAD_C(g2, nq, nk0, nv0, nka, nva, nkb, nvb); }
      COMPUTE(g0, q0v, k00, v00, ka0, va0, kb0, vb0, t);
      q0v = nq; k00 = nk0; v00 = nv0; ka0 = nka; va0 = nva; kb0 = nkb; vb0 = nvb;
      g0 = g1; g1 = g2; g2 = gnew;
    }
    {
      const int tl = (t + 3 < SEQ) ? t + 3 : SEQ - 1;
      const int tg = (t + 4 < SEQ) ? t + 4 : SEQ - 1;
      float4 gnew = gate[tg * BATCH + b];
      float4 nq, nk0, nka, nkb; float nv0, nva, nvb;
      { const float* YROW_t = YROW(tl); LOAD_C(g2, nq, nk0, nv0, nka, nva, nkb, nvb); }
      COMPUTE(g0, q1v, k01, v01, ka1, va1, kb1, vb1, t + 1);
      q1v = nq; k01 = nk0; v01 = nv0; ka1 = nka; va1 = nva; kb1 = nkb; vb1 = nvb;
      g0 = g1; g1 = g2; g2 = gnew;
    }
  }
#undef COMPUTE
#undef DO_SLOT
#undef DO_SLOT0
#undef LOAD_C

  if (c == ncMask) {   // last chunk owns M_final
    float* Mf = out + (int64_t)SEQ * BATCH * HID + (int64_t)b * 36864;
#pragma unroll
    for (int m = 0; m < 9; m++)
#pragma unroll
      for (int ii = 0; ii < 4; ii++)
        Mf[m * 4096 + (ib + ii) * 64 + j] = M[m][ii];
  }
}

// ---------------- launch ----------------
extern "C" void kernel_launch(void* const* d_in, const int* in_sizes, int n_in,
                              void* d_out, int out_size, void* d_ws, size_t ws_size,
                              hipStream_t stream)
{
  const float* X  = (const float*)d_in[0];
  const float* M0 = (const float*)d_in[1];
  const float* Wk = (const float*)d_in[2];
  const float* bk = (const float*)d_in[3];
  const float* Wv = (const float*)d_in[4];
  const float* bv = (const float*)d_in[5];
  const float* Wg = (const float*)d_in[6];
  const float* bg = (const float*)d_in[7];
  const float* Wq = (const float*)d_in[8];
  const float* bq = (const float*)d_in[9];

  char* ws = (char*)d_ws;
  short*  Xbf  = (short*)(ws + XBF_OFF);
  short*  Wbf  = (short*)(ws + WBF_OFF);
  float*  bb   = (float*)(ws + BB_OFF);
  float4* gate = (float4*)(ws + GATE_OFF);
  float*  Y    = (float*)(ws + Y_OFF);
  float*  out  = (float*)d_out;

  // chunk count: 8 if ws has room for a fresh ΔM region; else 4 chunks reusing
  // the Xbf/Wbf region (dead after gemm). ws_size is constant per deployment,
  // so this branch is deterministic across calls (graph-safe).
  int nc, ncShift; size_t dm_off;
  if (ws_size >= (size_t)DM8_END) { nc = 8; ncShift = 3; dm_off = DM8_OFF; }
  else                            { nc = 4; ncShift = 2; dm_off = 0; }
  const int L = SEQ / nc;
  float* DM = (float*)(ws + dm_off);

  prep_kernel<<<2048, 256, 0, stream>>>(X, Wk, bk, Wv, bv, Wg, bg, Wq, bq, Xbf, Wbf, bb);
  gate_kernel<<<ROWS / 4, 256, 0, stream>>>(X, Wg, bg, gate);
  dim3 gg(NPAD / 64, ROWS / 64);
  gemm_kernel<<<gg, 256, 0, stream>>>(Xbf, Wbf, bb, Y);
  chunk_accum_kernel<<<32 * nc * 8, 128, 0, stream>>>(Y, gate, DM, nc - 1, ncShift, L);
  prefix_kernel<<<(32 * 36864) / 256, 256, 0, stream>>>(M0, DM, nc);
  chunk_scan_kernel<<<32 * nc * 8, 128, 0, stream>>>(Y, gate, DM, out, nc - 1, ncShift, L);
}